// Round 7
// baseline (410.336 us; speedup 1.0000x reference)
//
#include <hip/hip_runtime.h>
#include <math.h>

#define BB 256
#define NN 200000
#define DD 128
#define INV_T 14.285714285714286f   // 1/0.07
#define CAP 3072                    // LDS hit-list entries (12 KB)

// ---------------------------------------------------------------------------
// d_ws layout (32-bit word offsets):
//   [0]        int   mode flag (0 = int32 masks, 1 = uint8/bool masks)
//   [64 ..]    float d1[256]
//   [320..]    float d2[256]
// ---------------------------------------------------------------------------
#define WS_FLAG 0
#define WS_D1   64
#define WS_D2   320

__global__ __launch_bounds__(64) void la_zero(unsigned* __restrict__ wsu) {
    const unsigned t = threadIdx.x;
    if (t == 0) wsu[WS_FLAG] = 0u;
    float* wsf = (float*)wsu;
    for (unsigned i = t; i < 512; i += 64) wsf[WS_D1 + i] = 0.f;
}

// Parallel dtype detection: scan first 50000 32-bit words (= 200000 bytes,
// in-bounds under both interpretations). Packed bool bytes give word values
// > 1; int32 bools are strictly 0/1.
__global__ __launch_bounds__(256) void la_detect(const unsigned* __restrict__ mbg_w,
                                                 unsigned* __restrict__ wsu) {
    const unsigned g = blockIdx.x * 256u + threadIdx.x;   // 64 blocks = 16384 thr
    int any = 0;
    for (unsigned i = g; i < 50000u; i += 16384u) any |= (mbg_w[i] > 1u) ? 1 : 0;
    if (any) atomicOr((int*)wsu + WS_FLAG, 1);
}

// Wave-per-hit cooperative dot (float2/lane vs LDS-staged code row), exp,
// accumulate into per-thread partials (lane 0 holds them).
__device__ __forceinline__ void process_hits(const float* __restrict__ bank,
                                             const void* __restrict__ mint_v,
                                             const unsigned* __restrict__ s_ent,
                                             int cnt, int flag, int b,
                                             const float2* __restrict__ code2,
                                             float scale, unsigned lane,
                                             unsigned wid, float& l1, float& l2) {
    for (int i = (int)wid; i < cnt; i += 4) {
        const unsigned n = s_ent[i];
        const float2 cv = code2[lane];
        const float2 bv = ((const float2*)bank)[(size_t)n * 64u + lane];
        float d = fmaf(cv.x, bv.x, cv.y * bv.y);
#pragma unroll
        for (int off = 32; off > 0; off >>= 1) d += __shfl_down(d, off, 64);
        if (lane == 0) {
            const float e = __expf(d * scale);
            l1 += e;
            const unsigned im = (flag == 0)
                ? ((const unsigned*)mint_v)[(size_t)b * NN + n]
                : (unsigned)((const unsigned char*)mint_v)[(size_t)b * NN + n];
            if (im) l2 += e;
        }
    }
}

// Overflow path for LDS hit-list saturation: serial per-thread dot against
// the LDS-staged code row, accumulate straight into global d1/d2. Correct
// for arbitrary mask density; never taken at the actual ~6 hits/block.
__device__ __noinline__ void slow_hit(const float* __restrict__ bank,
                                      const void* __restrict__ mint_v,
                                      const float* __restrict__ code_s,
                                      unsigned n, int flag, int b, float scale,
                                      float* __restrict__ wsf) {
    const float* brow = bank + (size_t)n * DD;
    float d = 0.f;
    for (int q = 0; q < DD; ++q) d = fmaf(code_s[q], brow[q], d);
    const float e = __expf(d * scale);
    atomicAdd(&wsf[WS_D1 + b], e);
    const unsigned im = (flag == 0)
        ? ((const unsigned*)mint_v)[(size_t)b * NN + n]
        : (unsigned)((const unsigned char*)mint_v)[(size_t)b * NN + n];
    if (im) atomicAdd(&wsf[WS_D2 + b], e);
}

// Fused scan + gather. Block = (slice s, row b): b is block-uniform, so the
// code row, scale, and d1/d2 targets are uniform. Hits go to an LDS list.
// BARRIER-FREE SCAN: no ballots / cross-lane ops in the scan loop, so lane
// divergence is correctness-harmless; overflow (pos >= CAP) is handled
// inline via slow_hit, so no flush barriers are needed and the 100 KB/block
// mask stream pipelines without interruption (round-6 version had 13
// per-iteration __syncthreads, each draining vmcnt).
__global__ __launch_bounds__(256) void la_fused(const float* __restrict__ codes,
                                                const float* __restrict__ bank,
                                                const void* __restrict__ mbg_v,
                                                const void* __restrict__ mint_v,
                                                unsigned* __restrict__ wsu) {
    __shared__ __align__(16) float code_s[DD];
    __shared__ unsigned s_ent[CAP];
    __shared__ unsigned s_cnt;
    __shared__ float s_red[8];
    __shared__ float s_scale;

    const int t = threadIdx.x;
    const unsigned lane = (unsigned)(t & 63);
    const unsigned wid = (unsigned)(t >> 6);
    const int s = blockIdx.x;    // slice 0..7
    const int b = blockIdx.y;    // row 0..255
    const int flag = (int)((volatile unsigned*)wsu)[WS_FLAG];
    float* wsf = (float*)wsu;

    // ---- prologue: stage code row, block-uniform scale = INV_T/||code||
    if (t == 0) s_cnt = 0u;
    float c = (t < DD) ? codes[b * DD + t] : 0.f;
    if (t < DD) code_s[t] = c;
    float sq = c * c;
#pragma unroll
    for (int off = 32; off > 0; off >>= 1) sq += __shfl_down(sq, off, 64);
    if (lane == 0) s_red[wid] = sq;
    __syncthreads();
    if (t == 0) s_scale = rsqrtf(s_red[0] + s_red[1] + s_red[2] + s_red[3]) * INV_T;
    __syncthreads();
    const float scale = s_scale;
    const float2* code2 = (const float2*)code_s;

    float l1 = 0.f, l2 = 0.f;

    if (flag == 0) {
        // int32 masks: row = 50000 uint4, slice = 6250 uint4 (exact).
        // 7 iterations x 1024 uint4 (4 per thread, all 4 loads in flight).
        const uint4* row = (const uint4*)((const char*)mbg_v + (size_t)b * (NN * 4)) + s * 6250;
        const int n_base = s * 25000;
        for (int it = 0; it < 7; ++it) {
            const int idx0 = it * 1024 + t;
            uint4 v[4];
#pragma unroll
            for (int k = 0; k < 4; ++k) {
                const int idx = idx0 + k * 256;
                v[k] = make_uint4(0u, 0u, 0u, 0u);
                if (idx < 6250) v[k] = row[idx];
            }
#pragma unroll
            for (int k = 0; k < 4; ++k) {
                const unsigned gw[4] = {v[k].x, v[k].y, v[k].z, v[k].w};
                const int idx = idx0 + k * 256;
#pragma unroll
                for (int j = 0; j < 4; ++j) {
                    if (gw[j] != 0u) {
                        const unsigned n = (unsigned)(n_base + idx * 4 + j);
                        unsigned pos = atomicAdd(&s_cnt, 1u);
                        if (pos < CAP) s_ent[pos] = n;
                        else slow_hit(bank, mint_v, code_s, n, flag, b, scale, wsf);
                    }
                }
            }
        }
    } else {
        // bool-byte masks: row = 12500 uint4; slice = 1563 (last 1559).
        // 2 iterations x 4 guarded loads per thread, 16 elems each.
        const uint4* rowb = (const uint4*)((const char*)mbg_v + (size_t)b * NN);
        const int w0 = s * 1563;
        const int wend = (s == 7) ? 12500 : (w0 + 1563);
        for (int it = 0; it < 2; ++it) {
            const int idx0 = w0 + it * 1024 + t;
            uint4 v[4];
#pragma unroll
            for (int k = 0; k < 4; ++k) {
                const int idx = idx0 + k * 256;
                v[k] = make_uint4(0u, 0u, 0u, 0u);
                if (idx < wend) v[k] = rowb[idx];
            }
#pragma unroll
            for (int k = 0; k < 4; ++k) {
                const unsigned gw[4] = {v[k].x, v[k].y, v[k].z, v[k].w};
                const int idx = idx0 + k * 256;
#pragma unroll
                for (int j = 0; j < 16; ++j) {
                    if (((gw[j >> 2] >> ((j & 3) * 8)) & 0xffu) != 0u) {
                        const unsigned n = (unsigned)(idx * 16 + j);
                        unsigned pos = atomicAdd(&s_cnt, 1u);
                        if (pos < CAP) s_ent[pos] = n;
                        else slow_hit(bank, mint_v, code_s, n, flag, b, scale, wsf);
                    }
                }
            }
        }
    }

    // ---- tail: process hits (wave-per-hit), reduce, 2 atomics per block
    __syncthreads();
    int cnt = (int)s_cnt;
    if (cnt > CAP) cnt = CAP;
    process_hits(bank, mint_v, s_ent, cnt, flag, b, code2, scale, lane, wid, l1, l2);

#pragma unroll
    for (int off = 32; off > 0; off >>= 1) {
        l1 += __shfl_down(l1, off, 64);
        l2 += __shfl_down(l2, off, 64);
    }
    __syncthreads();
    if (lane == 0) { s_red[wid] = l1; s_red[4 + wid] = l2; }
    __syncthreads();
    if (t == 0) {
        atomicAdd(&wsf[WS_D1 + b], s_red[0] + s_red[1] + s_red[2] + s_red[3]);
        atomicAdd(&wsf[WS_D2 + b], s_red[4] + s_red[5] + s_red[6] + s_red[7]);
    }
}

__global__ __launch_bounds__(256) void la_final(const float* __restrict__ d1,
                                                const float* __restrict__ d2,
                                                float* __restrict__ out) {
    __shared__ float red[4];
    const int t = threadIdx.x;  // == row index, BB == 256
    float v = logf(d1[t]) - logf(d2[t]);
#pragma unroll
    for (int off = 32; off > 0; off >>= 1) v += __shfl_down(v, off, 64);
    if ((t & 63) == 0) red[t >> 6] = v;
    __syncthreads();
    if (t == 0) out[0] = (red[0] + red[1] + red[2] + red[3]) / (float)BB;
}

extern "C" void kernel_launch(void* const* d_in, const int* in_sizes, int n_in,
                              void* d_out, int out_size, void* d_ws, size_t ws_size,
                              hipStream_t stream) {
    const float* codes = (const float*)d_in[0];
    const float* bank  = (const float*)d_in[1];
    const void*  mbg   = d_in[2];
    const void*  mit   = d_in[3];

    unsigned* wsu = (unsigned*)d_ws;
    float*    wsf = (float*)d_ws;

    la_zero<<<1, 64, 0, stream>>>(wsu);
    la_detect<<<64, 256, 0, stream>>>((const unsigned*)mbg, wsu);
    la_fused<<<dim3(8, BB), 256, 0, stream>>>(codes, bank, mbg, mit, wsu);
    la_final<<<1, 256, 0, stream>>>(wsf + WS_D1, wsf + WS_D2, (float*)d_out);
}